// Round 9
// baseline (103.127 us; speedup 1.0000x reference)
//
#include <hip/hip_runtime.h>

// LengthRegulator, round 9: phase-separated streams.
//   prep   : cumsum + searchsorted -> idx (-1 for masked rows), mel_len.
//   fillK  : writes zeros to masked rows only (REGULAR stores, pure-write phase
//            at fill rate ~6.85 TB/s; no read stream to thrash L2).
//   gatherK: writes live rows only (NT stores + x reads; the only mixed phase).
// Rationale: R5-R8 cluster at 88-90us with a single mixed kernel; 452 MB at
// 5.1 TB/s effective. Phase separation lets 56% of the write volume run at the
// measured pure-fill rate.
// B=32, T=1024, C=384, MAX_LEN=8192. Durations arrive as int32.

#define BB 32
#define TT 1024
#define CC 384
#define MAXLEN 8192
#define OUT0 (BB * MAXLEN * CC)   // 100663296 floats
#define QPR (CC / 4)              // 96 float4 per row

typedef float f32x4 __attribute__((ext_vector_type(4)));

// ---------------- Kernel 1: prep (one block per batch) ----------------
__global__ __launch_bounds__(256) void lr_prep(const int4* __restrict__ dur4,
                                               int* __restrict__ idx,
                                               float* __restrict__ mel_out) {
    __shared__ int cum[TT];
    __shared__ int wsum[4];
    const int b = blockIdx.x, t = threadIdx.x, lane = t & 63, w = t >> 6;

    int4 d = dur4[b * (TT / 4) + t];
    int s0 = d.x, s1 = s0 + d.y, s2 = s1 + d.z, s3 = s2 + d.w;
    int v = s3;
    #pragma unroll
    for (int dd = 1; dd < 64; dd <<= 1) {
        int u = __shfl_up(v, dd);
        if (lane >= dd) v += u;
    }
    if (lane == 63) wsum[w] = v;
    __syncthreads();
    int prefix = 0;
    #pragma unroll
    for (int i = 0; i < 4; ++i) prefix += (i < w) ? wsum[i] : 0;
    const int base = prefix + v - s3;          // exclusive prefix for this thread's 4
    cum[4 * t + 0] = base + s0;
    cum[4 * t + 1] = base + s1;
    cum[4 * t + 2] = base + s2;
    cum[4 * t + 3] = base + s3;
    __syncthreads();
    const int ml = cum[TT - 1];
    if (t == 0) mel_out[b] = (float)ml;

    #pragma unroll
    for (int k = 0; k < MAXLEN / 256; ++k) {   // 32 positions per thread
        int p = t + k * 256;
        int r = -1;
        if (p < ml) {
            int lo = 0, hi = TT;
            while (lo < hi) {                  // lo = count(cum <= p)
                int mid = (lo + hi) >> 1;
                if (cum[mid] <= p) lo = mid + 1; else hi = mid;
            }
            r = (lo < TT - 1) ? lo : (TT - 1);
        }
        idx[b * MAXLEN + p] = r;
    }
}

// ---------------- Kernel 2a: fill masked rows (regular stores, no reads) ----------------
__global__ void lr_fill(const int* __restrict__ idx,
                        f32x4* __restrict__ out4) {
    const unsigned HALF = (unsigned)BB * MAXLEN * QPR / 2;  // 12582912
    const unsigned stride = gridDim.x * blockDim.x;
    const f32x4 z = (f32x4)0.f;
    for (unsigned q = blockIdx.x * blockDim.x + threadIdx.x; q < HALF; q += stride) {
        const unsigned q2 = q + HALF;
        unsigned row1 = q / QPR;
        unsigned row2 = q2 / QPR;
        if (idx[row1] < 0) out4[q]  = z;
        if (idx[row2] < 0) out4[q2] = z;
    }
}

// ---------------- Kernel 2b: gather live rows (NT stores) ----------------
__global__ void lr_gather(const f32x4* __restrict__ x4,
                          const int* __restrict__ idx,
                          f32x4* __restrict__ out4) {
    const unsigned HALF = (unsigned)BB * MAXLEN * QPR / 2;  // 12582912
    const unsigned stride = gridDim.x * blockDim.x;
    for (unsigned q = blockIdx.x * blockDim.x + threadIdx.x; q < HALF; q += stride) {
        const unsigned q2 = q + HALF;
        unsigned row1 = q / QPR,  ln1 = q  - row1 * QPR;
        unsigned row2 = q2 / QPR, ln2 = q2 - row2 * QPR;
        int i1 = idx[row1];
        int i2 = idx[row2];
        if (i1 >= 0) {
            f32x4 v1 = x4[((size_t)(row1 >> 13) * TT + (unsigned)i1) * QPR + ln1];
            __builtin_nontemporal_store(v1, &out4[q]);
        }
        if (i2 >= 0) {
            f32x4 v2 = x4[((size_t)(row2 >> 13) * TT + (unsigned)i2) * QPR + ln2];
            __builtin_nontemporal_store(v2, &out4[q2]);
        }
    }
}

extern "C" void kernel_launch(void* const* d_in, const int* in_sizes, int n_in,
                              void* d_out, int out_size, void* d_ws, size_t ws_size,
                              hipStream_t stream) {
    const float* x   = (const float*)d_in[0];
    const int*   dur = (const int*)d_in[1];   // int64 in reference -> int32 on device
    float* out = (float*)d_out;

    int* idx = (int*)d_ws;                    // B*MAXLEN int32 = 1 MB

    lr_prep<<<BB, 256, 0, stream>>>((const int4*)dur, idx, out + OUT0);
    lr_fill<<<4096, 256, 0, stream>>>(idx, (f32x4*)out);
    lr_gather<<<4096, 256, 0, stream>>>((const f32x4*)x, idx, (f32x4*)out);
}